// Round 1
// baseline (492.534 us; speedup 1.0000x reference)
//
#include <hip/hip_runtime.h>

// Problem constants (from reference): B=16384, F=40, D=32
#define B_TOT   16384
#define FF      40
#define DD      32
#define NB      4            // batch elements per block
#define NTHREADS 128         // 2 waves

// LDS:
//  s_g : g tile [NB][F][F] = 6400 floats (25.6 KB); reused later as aggr
//        with padded layout [NB][F][36] (5760 floats)
//  s_ho: h_out tile [NB][F][D] = 5120 floats (20.5 KB)
// total 46 KB -> 3 blocks/CU

__global__ __launch_bounds__(NTHREADS, 2)
void graphlayer_fused(const float* __restrict__ g,
                      const float* __restrict__ h,
                      const float* __restrict__ Win,
                      const float* __restrict__ Wout,
                      const float* __restrict__ bias,
                      float* __restrict__ out)
{
    __shared__ __attribute__((aligned(16))) float s_g[NB * FF * FF];   // 6400
    __shared__ __attribute__((aligned(16))) float s_ho[NB * FF * DD];  // 5120

    const int t  = threadIdx.x;
    const int b0 = blockIdx.x * NB;

    // ---------------- Phase 0: cooperative copy of g tile (contiguous) ----
    {
        const float4* gsrc = (const float4*)(g + (size_t)b0 * (FF * FF));
        float4* gdst = (float4*)s_g;
        #pragma unroll
        for (int i = 0; i < 12; ++i)
            gdst[t + i * NTHREADS] = gsrc[t + i * NTHREADS];
        if (t < 64)
            gdst[t + 12 * NTHREADS] = gsrc[t + 12 * NTHREADS]; // 1600 float4 total
    }

    // ---------------- Phase 1: h_out[b][f][d] = sum_e Wout[f][d][e]*h[b][f][e]
    // mapping: d1 = t>>2 (0..31), eq = t&3 (e-chunk of 8)
    {
        const int d1 = t >> 2;
        const int eq = t & 3;
        for (int f = 0; f < FF; ++f) {
            const float4* wr = (const float4*)(Wout + f * (DD * DD) + d1 * DD + eq * 8);
            float4 w0 = wr[0], w1 = wr[1];           // coalesced 32B/lane
            float part[NB];
            #pragma unroll
            for (int blx = 0; blx < NB; ++blx) {
                const float4* hr = (const float4*)(h + (size_t)(b0 + blx) * (FF * DD)
                                                     + f * DD + eq * 8);
                float4 h0 = hr[0], h1 = hr[1];       // broadcast across d-lanes
                part[blx] = w0.x * h0.x + w0.y * h0.y + w0.z * h0.z + w0.w * h0.w
                          + w1.x * h1.x + w1.y * h1.y + w1.z * h1.z + w1.w * h1.w;
            }
            // butterfly-reduce partial dots across the e-quad (lanes eq=0..3)
            #pragma unroll
            for (int blx = 0; blx < NB; ++blx) {
                float v = part[blx];
                v += __shfl_xor(v, 1);
                v += __shfl_xor(v, 2);
                part[blx] = v;
            }
            // lane writes the batch element matching its eq
            float res = part[0];
            res = (eq == 1) ? part[1] : res;
            res = (eq == 2) ? part[2] : res;
            res = (eq == 3) ? part[3] : res;
            s_ho[eq * (FF * DD) + f * DD + d1] = res;
        }
    }
    __syncthreads();   // s_ho complete, g tile copy complete

    // ---------------- Phase 2: aggr[b][f][d] = sum_gg g[b][f][gg]*h_out[b][gg][d]
    // mapping: bl = t>>5, dg = (t>>3)&3 (d-tile of 8), fg = t&7 (f in {fg+8i})
    {
        const int bl    = t >> 5;
        const int local = t & 31;
        const int dg    = local >> 3;
        const int fg    = local & 7;
        const int d0    = dg << 3;

        const float* sgb  = s_g  + bl * (FF * FF);
        const float* shob = s_ho + bl * (FF * DD);

        float acc2[5][8];
        #pragma unroll
        for (int i = 0; i < 5; ++i)
            #pragma unroll
            for (int j = 0; j < 8; ++j)
                acc2[i][j] = 0.f;

        for (int gc = 0; gc < 10; ++gc) {
            const int gg = gc << 2;
            // load h_out[gg..gg+3][d0..d0+7]
            float hor[4][8];
            #pragma unroll
            for (int j = 0; j < 4; ++j) {
                const float4* p = (const float4*)(shob + (gg + j) * DD + d0);
                float4 x0 = p[0], x1 = p[1];
                hor[j][0] = x0.x; hor[j][1] = x0.y; hor[j][2] = x0.z; hor[j][3] = x0.w;
                hor[j][4] = x1.x; hor[j][5] = x1.y; hor[j][6] = x1.z; hor[j][7] = x1.w;
            }
            #pragma unroll
            for (int i = 0; i < 5; ++i) {
                const int f = fg + (i << 3);
                float4 gv = *(const float4*)(sgb + f * FF + gg);
                #pragma unroll
                for (int j = 0; j < 8; ++j) {
                    acc2[i][j] += gv.x * hor[0][j];
                    acc2[i][j] += gv.y * hor[1][j];
                    acc2[i][j] += gv.z * hor[2][j];
                    acc2[i][j] += gv.w * hor[3][j];
                }
            }
        }
        __syncthreads();   // everyone done reading g tile
        // write aggr into the s_g region, padded layout [bl][f][36]
        #pragma unroll
        for (int i = 0; i < 5; ++i) {
            const int f = fg + (i << 3);
            float* p = s_g + bl * (FF * 36) + f * 36 + d0;
            ((float4*)p)[0] = make_float4(acc2[i][0], acc2[i][1], acc2[i][2], acc2[i][3]);
            ((float4*)p)[1] = make_float4(acc2[i][4], acc2[i][5], acc2[i][6], acc2[i][7]);
        }
    }
    __syncthreads();

    // ---------------- Phase 3: a[b][f][d] = bias[d] + sum_e Win[f][d][e]*aggr[b][f][e]
    {
        const int d1 = t >> 2;
        const int eq = t & 3;
        const float biasv = bias[d1];
        for (int f = 0; f < FF; ++f) {
            const float4* wr = (const float4*)(Win + f * (DD * DD) + d1 * DD + eq * 8);
            float4 w0 = wr[0], w1 = wr[1];
            float part[NB];
            #pragma unroll
            for (int blx = 0; blx < NB; ++blx) {
                const float4* ar = (const float4*)(s_g + blx * (FF * 36) + f * 36 + eq * 8);
                float4 a0 = ar[0], a1 = ar[1];       // LDS broadcast
                part[blx] = w0.x * a0.x + w0.y * a0.y + w0.z * a0.z + w0.w * a0.w
                          + w1.x * a1.x + w1.y * a1.y + w1.z * a1.z + w1.w * a1.w;
            }
            #pragma unroll
            for (int blx = 0; blx < NB; ++blx) {
                float v = part[blx];
                v += __shfl_xor(v, 1);
                v += __shfl_xor(v, 2);
                part[blx] = v;
            }
            float res = part[0];
            res = (eq == 1) ? part[1] : res;
            res = (eq == 2) ? part[2] : res;
            res = (eq == 3) ? part[3] : res;
            out[(size_t)(b0 + eq) * (FF * DD) + f * DD + d1] = res + biasv;
        }
    }
}

extern "C" void kernel_launch(void* const* d_in, const int* in_sizes, int n_in,
                              void* d_out, int out_size, void* d_ws, size_t ws_size,
                              hipStream_t stream) {
    const float* g    = (const float*)d_in[0];
    const float* h    = (const float*)d_in[1];
    const float* Win  = (const float*)d_in[2];
    const float* Wout = (const float*)d_in[3];
    const float* bias = (const float*)d_in[4];
    float* out = (float*)d_out;

    dim3 grid(B_TOT / NB);
    dim3 block(NTHREADS);
    graphlayer_fused<<<grid, block, 0, stream>>>(g, h, Win, Wout, bias, out);
}

// Round 2
// 491.147 us; speedup vs baseline: 1.0028x; 1.0028x over previous
//
#include <hip/hip_runtime.h>

// B=16384, F=40, D=32, fp32 throughout.
#define B_TOT    16384
#define FF       40
#define DD       32
#define NB       4            // batch elements per block (one wave each in phase 2)
#define NTHREADS 256          // 4 waves
#define HOP      36           // padded row stride for s_ho (floats)
#define HOB      (FF * HOP)   // per-b block in s_ho = 1440 floats

// LDS: s_ho [NB][FF][HOP] = 23 KB. launch_bounds(256,4) -> <=128 VGPR ->
// 4 blocks/CU = 16 waves/CU (vs 6 in R0).

__global__ __launch_bounds__(NTHREADS, 4)
void graphlayer_fused(const float* __restrict__ g,
                      const float* __restrict__ h,
                      const float* __restrict__ Win,
                      const float* __restrict__ Wout,
                      const float* __restrict__ bias,
                      float* __restrict__ out)
{
    __shared__ __attribute__((aligned(16))) float s_ho[NB * HOB];  // 5760 floats

    const int t  = threadIdx.x;
    const int b0 = blockIdx.x * NB;

    // ---- Phase 1: h_out[b][f][d] = sum_e Wout[f][d][e] * h[b][f][e] ----
    {
        const int fh = t >> 7;          // 0..1 (f-half)
        const int d1 = (t >> 2) & 31;   // 0..31
        const int eq = t & 3;           // 0..3 (e-chunk of 8)
        for (int fi = 0; fi < 20; ++fi) {
            const int f = fh * 20 + fi;
            const float4* wr = (const float4*)(Wout + f * (DD * DD) + d1 * DD + eq * 8);
            float4 w0 = wr[0], w1 = wr[1];
            float part[NB];
            #pragma unroll
            for (int blx = 0; blx < NB; ++blx) {
                const float4* hr = (const float4*)(h + (size_t)(b0 + blx) * (FF * DD)
                                                     + f * DD + eq * 8);
                float4 h0 = hr[0], h1 = hr[1];
                part[blx] = w0.x * h0.x + w0.y * h0.y + w0.z * h0.z + w0.w * h0.w
                          + w1.x * h1.x + w1.y * h1.y + w1.z * h1.z + w1.w * h1.w;
            }
            #pragma unroll
            for (int blx = 0; blx < NB; ++blx) {
                float v = part[blx];
                v += __shfl_xor(v, 1);
                v += __shfl_xor(v, 2);
                part[blx] = v;
            }
            float res = part[0];
            res = (eq == 1) ? part[1] : res;
            res = (eq == 2) ? part[2] : res;
            res = (eq == 3) ? part[3] : res;
            s_ho[eq * HOB + f * HOP + d1] = res;
        }
    }
    __syncthreads();

    // ---- Phase 2: aggr[b][f][d] = sum_gg g[b][f][gg] * h_out[b][gg][d] ----
    {
        const int w  = t >> 6;          // wave -> b
        const int l  = t & 63;
        const int dg = l >> 3;          // d-quad 0..7
        const int fg = l & 7;           // f mod 8

        const float* gb   = g + (size_t)(b0 + w) * (FF * FF);
        const float* shob = s_ho + w * HOB;

        float acc[5][4];
        #pragma unroll
        for (int i = 0; i < 5; ++i)
            #pragma unroll
            for (int j = 0; j < 4; ++j) acc[i][j] = 0.f;

        for (int gc = 0; gc < 10; ++gc) {
            const int gg = gc << 2;
            float4 hv0 = *(const float4*)(shob + (gg + 0) * HOP + dg * 4);
            float4 hv1 = *(const float4*)(shob + (gg + 1) * HOP + dg * 4);
            float4 hv2 = *(const float4*)(shob + (gg + 2) * HOP + dg * 4);
            float4 hv3 = *(const float4*)(shob + (gg + 3) * HOP + dg * 4);
            #pragma unroll
            for (int i = 0; i < 5; ++i) {
                const int f = fg + (i << 3);
                float4 gv = *(const float4*)(gb + f * FF + gg);
                acc[i][0] += gv.x * hv0.x + gv.y * hv1.x + gv.z * hv2.x + gv.w * hv3.x;
                acc[i][1] += gv.x * hv0.y + gv.y * hv1.y + gv.z * hv2.y + gv.w * hv3.y;
                acc[i][2] += gv.x * hv0.z + gv.y * hv1.z + gv.z * hv2.z + gv.w * hv3.z;
                acc[i][3] += gv.x * hv0.w + gv.y * hv1.w + gv.z * hv2.w + gv.w * hv3.w;
            }
        }
        #pragma unroll
        for (int i = 0; i < 5; ++i) {
            const int f = fg + (i << 3);
            *(float4*)(s_ho + w * HOB + f * HOP + dg * 4) =
                make_float4(acc[i][0], acc[i][1], acc[i][2], acc[i][3]);
        }
    }
    __syncthreads();

    // ---- Phase 3: a[b][f][d] = bias[d] + sum_e Win[f][d][e] * aggr[b][f][e] ----
    {
        const int fh = t >> 7;
        const int d1 = (t >> 2) & 31;
        const int eq = t & 3;
        const float biasv = bias[d1];
        for (int fi = 0; fi < 20; ++fi) {
            const int f = fh * 20 + fi;
            const float4* wr = (const float4*)(Win + f * (DD * DD) + d1 * DD + eq * 8);
            float4 w0 = wr[0], w1 = wr[1];
            float part[NB];
            #pragma unroll
            for (int blx = 0; blx < NB; ++blx) {
                const float4* ar = (const float4*)(s_ho + blx * HOB + f * HOP + eq * 8);
                float4 a0 = ar[0], a1 = ar[1];
                part[blx] = w0.x * a0.x + w0.y * a0.y + w0.z * a0.z + w0.w * a0.w
                          + w1.x * a1.x + w1.y * a1.y + w1.z * a1.z + w1.w * a1.w;
            }
            #pragma unroll
            for (int blx = 0; blx < NB; ++blx) {
                float v = part[blx];
                v += __shfl_xor(v, 1);
                v += __shfl_xor(v, 2);
                part[blx] = v;
            }
            float res = part[0];
            res = (eq == 1) ? part[1] : res;
            res = (eq == 2) ? part[2] : res;
            res = (eq == 3) ? part[3] : res;
            out[(size_t)(b0 + eq) * (FF * DD) + f * DD + d1] = res + biasv;
        }
    }
}

extern "C" void kernel_launch(void* const* d_in, const int* in_sizes, int n_in,
                              void* d_out, int out_size, void* d_ws, size_t ws_size,
                              hipStream_t stream) {
    const float* g    = (const float*)d_in[0];
    const float* h    = (const float*)d_in[1];
    const float* Win  = (const float*)d_in[2];
    const float* Wout = (const float*)d_in[3];
    const float* bias = (const float*)d_in[4];
    float* out = (float*)d_out;

    dim3 grid(B_TOT / NB);
    dim3 block(NTHREADS);
    graphlayer_fused<<<grid, block, 0, stream>>>(g, h, Win, Wout, bias, out);
}